// Round 1
// baseline (74.675 us; speedup 1.0000x reference)
//
#include <hip/hip_runtime.h>

#define B 64
#define N 1024
#define G 256
#define H 512

// ---------------------------------------------------------------------------
// Kernel 1: stable top-k (k=G=256) of pt_weight per batch via O(N^2) ranking,
// then gather selected points directly into the gpts output section.
// rank_i = #{ j : w_j > w_i  or (w_j == w_i and j < i) }  -> exact lax.top_k
// order (descending value, ties broken by lower index).
// ---------------------------------------------------------------------------
__global__ __launch_bounds__(1024) void topk_gather_kernel(
    const float* __restrict__ pts,        // (B,3,N)
    const float* __restrict__ pt_weight,  // (B,N)
    float* __restrict__ out_gpts)         // (B,G,3)
{
    const int b = blockIdx.x;
    const int i = threadIdx.x;

    __shared__ float w[N];
    w[i] = pt_weight[b * N + i];
    __syncthreads();

    const float wi = w[i];
    int rank = 0;
#pragma unroll 8
    for (int j = 0; j < N; ++j) {
        const float wj = w[j];
        rank += (wj > wi) || (wj == wi && j < i);
    }

    if (rank < G) {
        float* dst = out_gpts + ((size_t)b * G + rank) * 3;
        dst[0] = pts[b * 3 * N + 0 * N + i];
        dst[1] = pts[b * 3 * N + 1 * N + i];
        dst[2] = pts[b * 3 * N + 2 * N + i];
    }
}

// ---------------------------------------------------------------------------
// Kernel 2: per hypothesis h: build plane from 3 gathered points, normalize,
// score = sum_n exp(-50 * dist^2), loss = min(||n-t||^2, ||n+t||^2).
// One block = one batch x 16 hypotheses; pts[b] staged in LDS (12 KB).
// Each wave owns 4 hypotheses; 64 lanes x 16 points each, shuffle reduce.
// ---------------------------------------------------------------------------
#define HB 16  // hypotheses per block

__global__ __launch_bounds__(256) void plane_score_kernel(
    const float* __restrict__ pts,      // (B,3,N)
    const float* __restrict__ target,   // (B,3)
    const int* __restrict__ sel_idx,    // (B,H,3)
    const float* __restrict__ gpts,     // (B,G,3)  [from d_out]
    float* __restrict__ score,          // (B,H)
    float* __restrict__ loss,           // (B,H)
    float* __restrict__ normals)        // (B,H,3)
{
    const int blk = blockIdx.x;
    const int b = blk / (H / HB);
    const int hb = blk % (H / HB);

    __shared__ float sp[3 * N];  // [c][n]
    for (int t = threadIdx.x; t < 3 * N; t += 256)
        sp[t] = pts[b * 3 * N + t];
    __syncthreads();

    const int wave = threadIdx.x >> 6;
    const int lane = threadIdx.x & 63;

    const float tx = target[b * 3 + 0];
    const float ty = target[b * 3 + 1];
    const float tz = target[b * 3 + 2];

    for (int hi = 0; hi < HB / 4; ++hi) {
        const int h = hb * HB + wave * (HB / 4) + hi;

        const int* si = sel_idx + ((size_t)b * H + h) * 3;
        const int g0 = si[0], g1 = si[1], g2 = si[2];
        const float* gp = gpts + (size_t)b * G * 3;

        const float p0x = gp[g0 * 3 + 0], p0y = gp[g0 * 3 + 1], p0z = gp[g0 * 3 + 2];
        const float p1x = gp[g1 * 3 + 0], p1y = gp[g1 * 3 + 1], p1z = gp[g1 * 3 + 2];
        const float p2x = gp[g2 * 3 + 0], p2y = gp[g2 * 3 + 1], p2z = gp[g2 * 3 + 2];

        const float e1x = p1x - p0x, e1y = p1y - p0y, e1z = p1z - p0z;
        const float e2x = p2x - p0x, e2y = p2y - p0y, e2z = p2z - p0z;

        float nx = e1y * e2z - e1z * e2y;
        float ny = e1z * e2x - e1x * e2z;
        float nz = e1x * e2y - e1y * e2x;
        float d  = -(nx * p0x + ny * p0y + nz * p0z);

        // all_zero -> ones (degenerate triangle)
        if (nx == 0.f && ny == 0.f && nz == 0.f && d == 0.f) {
            nx = ny = nz = d = 1.f;
        }

        const float inv = 1.0f / sqrtf(nx * nx + ny * ny + nz * nz);
        nx *= inv; ny *= inv; nz *= inv; d *= inv;

        float acc = 0.f;
#pragma unroll
        for (int k = 0; k < N / 64; ++k) {
            const int n = lane + 64 * k;
            const float dist = fabsf(nx * sp[n] + ny * sp[N + n] + nz * sp[2 * N + n] + d);
            acc += expf(-50.0f * dist * dist);
        }
#pragma unroll
        for (int off = 32; off; off >>= 1) acc += __shfl_xor(acc, off);

        const float l1 = (nx - tx) * (nx - tx) + (ny - ty) * (ny - ty) + (nz - tz) * (nz - tz);
        const float l2 = (nx + tx) * (nx + tx) + (ny + ty) * (ny + ty) + (nz + tz) * (nz + tz);
        const float l = fminf(l1, l2);

        if (lane == 0) {
            const int idx = b * H + h;
            score[idx] = acc;
            loss[idx] = l;
            normals[idx * 3 + 0] = nx;
            normals[idx * 3 + 1] = ny;
            normals[idx * 3 + 2] = nz;
        }
    }
}

// ---------------------------------------------------------------------------
// Kernel 3: per batch: argmax(score) (tie -> first index), stable softmax of
// 0.5*score, exp_loss = sum(loss*w)/sum(w), top_loss, pred.
// ---------------------------------------------------------------------------
__global__ __launch_bounds__(512) void finalize_kernel(
    const float* __restrict__ score,    // (B,H)
    const float* __restrict__ loss,     // (B,H)
    const float* __restrict__ normals,  // (B,H,3)
    float* __restrict__ out)            // [exp_loss(B) | top_loss(B) | pred(B,3) | gpts...]
{
    const int b = blockIdx.x;
    const int h = threadIdx.x;

    const float s = score[b * H + h];
    const float l = loss[b * H + h];

    __shared__ float sv[H];
    __shared__ int   sidx[H];
    __shared__ float sw[H];
    __shared__ float swl[H];

    sv[h] = s;
    sidx[h] = h;
    __syncthreads();

#pragma unroll
    for (int off = H / 2; off > 0; off >>= 1) {
        if (h < off) {
            const float v2 = sv[h + off];
            const int i2 = sidx[h + off];
            if (v2 > sv[h] || (v2 == sv[h] && i2 < sidx[h])) {
                sv[h] = v2;
                sidx[h] = i2;
            }
        }
        __syncthreads();
    }

    const float smax = sv[0];
    const int maxidx = sidx[0];

    const float wgt = expf(0.5f * (s - smax));
    sw[h] = wgt;
    swl[h] = wgt * l;
    __syncthreads();

#pragma unroll
    for (int off = H / 2; off > 0; off >>= 1) {
        if (h < off) {
            sw[h] += sw[h + off];
            swl[h] += swl[h + off];
        }
        __syncthreads();
    }

    if (h == 0) {
        out[b] = swl[0] / sw[0];                       // exp_loss
        out[B + b] = loss[b * H + maxidx];             // top_loss
        out[2 * B + b * 3 + 0] = normals[(b * H + maxidx) * 3 + 0];
        out[2 * B + b * 3 + 1] = normals[(b * H + maxidx) * 3 + 1];
        out[2 * B + b * 3 + 2] = normals[(b * H + maxidx) * 3 + 2];
    }
}

// ---------------------------------------------------------------------------
extern "C" void kernel_launch(void* const* d_in, const int* in_sizes, int n_in,
                              void* d_out, int out_size, void* d_ws, size_t ws_size,
                              hipStream_t stream) {
    const float* pts       = (const float*)d_in[0];  // (B,3,N)
    const float* target    = (const float*)d_in[1];  // (B,3)
    const float* pt_weight = (const float*)d_in[2];  // (B,N)
    const int*   sel_idx   = (const int*)d_in[3];    // (B,H,3)

    float* out = (float*)d_out;
    // layout: exp_loss[B] | top_loss[B] | pred[B*3] | gpts[B*G*3]
    float* out_gpts = out + B + B + 3 * B;  // offset 320

    float* ws      = (float*)d_ws;
    float* score   = ws;                  // B*H
    float* loss    = ws + B * H;          // B*H
    float* normals = ws + 2 * B * H;      // B*H*3

    topk_gather_kernel<<<B, 1024, 0, stream>>>(pts, pt_weight, out_gpts);
    plane_score_kernel<<<B * (H / HB), 256, 0, stream>>>(pts, target, sel_idx,
                                                         out_gpts, score, loss, normals);
    finalize_kernel<<<B, H, 0, stream>>>(score, loss, normals, out);
}

// Round 2
// 52.733 us; speedup vs baseline: 1.4161x; 1.4161x over previous
//
#include <hip/hip_runtime.h>

#define B 64
#define N 1024
#define G 256
#define H 512

// ---------------------------------------------------------------------------
// Kernel 1: stable top-k (k=G=256) of pt_weight per batch via O(N^2) ranking.
// 4 blocks per batch (256 threads each) so all 256 CUs get work.
// rank_i = #{ j : w_j > w_i  or (w_j == w_i and j < i) }  -> exact lax.top_k
// order (descending value, ties broken by lower index).
// ---------------------------------------------------------------------------
#define TKB 4  // blocks per batch

__global__ __launch_bounds__(256) void topk_gather_kernel(
    const float* __restrict__ pts,        // (B,3,N)
    const float* __restrict__ pt_weight,  // (B,N)
    float* __restrict__ out_gpts)         // (B,G,3)
{
    const int b = blockIdx.x / TKB;
    const int q = blockIdx.x % TKB;

    __shared__ float w[N];
    ((float4*)w)[threadIdx.x] = ((const float4*)(pt_weight + b * N))[threadIdx.x];
    __syncthreads();

    const int i = q * 256 + threadIdx.x;
    const float wi = w[i];

    int rank = 0;
#pragma unroll 8
    for (int j = 0; j < N; j += 4) {
        const float4 wj = *(const float4*)(w + j);  // broadcast LDS read
        rank += (wj.x > wi) || (wj.x == wi && (j + 0) < i);
        rank += (wj.y > wi) || (wj.y == wi && (j + 1) < i);
        rank += (wj.z > wi) || (wj.z == wi && (j + 2) < i);
        rank += (wj.w > wi) || (wj.w == wi && (j + 3) < i);
    }

    if (rank < G) {
        float* dst = out_gpts + ((size_t)b * G + rank) * 3;
        dst[0] = pts[b * 3 * N + 0 * N + i];
        dst[1] = pts[b * 3 * N + 1 * N + i];
        dst[2] = pts[b * 3 * N + 2 * N + i];
    }
}

// ---------------------------------------------------------------------------
// Kernel 2: per hypothesis: build plane from 3 gathered points, normalize,
// score = sum_n exp(-50*dist^2), loss = min(||n-t||^2, ||n+t||^2).
// One block = one batch x 16 hypotheses; pts[b] staged in LDS (12 KB).
// Each wave evaluates its 4 hypotheses SIMULTANEOUSLY per point load, so the
// 3 LDS reads per point amortize over 4 planes (VALU/exp-bound, not LDS).
// ---------------------------------------------------------------------------
#define HB 16  // hypotheses per block

__global__ __launch_bounds__(256) void plane_score_kernel(
    const float* __restrict__ pts,      // (B,3,N)
    const float* __restrict__ target,   // (B,3)
    const int* __restrict__ sel_idx,    // (B,H,3)
    const float* __restrict__ gpts,     // (B,G,3)  [from d_out]
    float* __restrict__ score,          // (B,H)
    float* __restrict__ loss,           // (B,H)
    float* __restrict__ normals)        // (B,H,3)
{
    const int blk = blockIdx.x;
    const int b = blk / (H / HB);
    const int hb = blk % (H / HB);

    __shared__ float sp[3 * N];  // [c][n]
    for (int t = threadIdx.x; t < 3 * N / 4; t += 256)
        ((float4*)sp)[t] = ((const float4*)(pts + (size_t)b * 3 * N))[t];
    __syncthreads();

    const int wave = threadIdx.x >> 6;
    const int lane = threadIdx.x & 63;

    const int h0 = hb * HB + wave * 4;  // this wave's 4 hypotheses
    const float* gp = gpts + (size_t)b * G * 3;

    float nx[4], ny[4], nz[4], pd[4], acc[4];

#pragma unroll
    for (int hh = 0; hh < 4; ++hh) {
        const int* si = sel_idx + ((size_t)b * H + h0 + hh) * 3;
        const int g0 = si[0], g1 = si[1], g2 = si[2];

        const float p0x = gp[g0 * 3 + 0], p0y = gp[g0 * 3 + 1], p0z = gp[g0 * 3 + 2];
        const float p1x = gp[g1 * 3 + 0], p1y = gp[g1 * 3 + 1], p1z = gp[g1 * 3 + 2];
        const float p2x = gp[g2 * 3 + 0], p2y = gp[g2 * 3 + 1], p2z = gp[g2 * 3 + 2];

        const float e1x = p1x - p0x, e1y = p1y - p0y, e1z = p1z - p0z;
        const float e2x = p2x - p0x, e2y = p2y - p0y, e2z = p2z - p0z;

        float x = e1y * e2z - e1z * e2y;
        float y = e1z * e2x - e1x * e2z;
        float z = e1x * e2y - e1y * e2x;
        float d = -(x * p0x + y * p0y + z * p0z);

        if (x == 0.f && y == 0.f && z == 0.f && d == 0.f) {
            x = y = z = d = 1.f;  // degenerate -> ones
        }

        const float inv = 1.0f / sqrtf(x * x + y * y + z * z);
        nx[hh] = x * inv; ny[hh] = y * inv; nz[hh] = z * inv; pd[hh] = d * inv;
        acc[hh] = 0.f;
    }

#pragma unroll
    for (int k = 0; k < N / 64; ++k) {
        const int n = lane + 64 * k;
        const float px = sp[n], py = sp[N + n], pz = sp[2 * N + n];
#pragma unroll
        for (int hh = 0; hh < 4; ++hh) {
            const float dist = fabsf(fmaf(nx[hh], px, fmaf(ny[hh], py, fmaf(nz[hh], pz, pd[hh]))));
            acc[hh] += __expf(-50.0f * dist * dist);
        }
    }

    const float tx = target[b * 3 + 0];
    const float ty = target[b * 3 + 1];
    const float tz = target[b * 3 + 2];

#pragma unroll
    for (int hh = 0; hh < 4; ++hh) {
        float a = acc[hh];
#pragma unroll
        for (int off = 32; off; off >>= 1) a += __shfl_xor(a, off);

        if (lane == 0) {
            const float x = nx[hh], y = ny[hh], z = nz[hh];
            const float l1 = (x - tx) * (x - tx) + (y - ty) * (y - ty) + (z - tz) * (z - tz);
            const float l2 = (x + tx) * (x + tx) + (y + ty) * (y + ty) + (z + tz) * (z + tz);
            const int idx = b * H + h0 + hh;
            score[idx] = a;
            loss[idx] = fminf(l1, l2);
            normals[idx * 3 + 0] = x;
            normals[idx * 3 + 1] = y;
            normals[idx * 3 + 2] = z;
        }
    }
}

// ---------------------------------------------------------------------------
// Kernel 3: per batch: argmax(score) (tie -> first idx), stable softmax of
// 0.5*score, exp_loss = sum(loss*w)/sum(w), top_loss, pred.
// Wave-shuffle reductions; 3 __syncthreads total.
// ---------------------------------------------------------------------------
__global__ __launch_bounds__(512) void finalize_kernel(
    const float* __restrict__ score,    // (B,H)
    const float* __restrict__ loss,     // (B,H)
    const float* __restrict__ normals,  // (B,H,3)
    float* __restrict__ out)            // [exp_loss(B) | top_loss(B) | pred(B,3) | gpts...]
{
    const int b = blockIdx.x;
    const int h = threadIdx.x;
    const int wave = h >> 6;
    const int lane = h & 63;

    const float s = score[b * H + h];
    const float l = loss[b * H + h];

    __shared__ float wv[8];
    __shared__ int   widx[8];
    __shared__ float s_max;
    __shared__ int   s_maxidx;
    __shared__ float sw[8], swl[8];

    // per-wave argmax (tie -> lower index)
    float v = s;
    int idx = h;
#pragma unroll
    for (int off = 32; off; off >>= 1) {
        const float v2 = __shfl_xor(v, off);
        const int i2 = __shfl_xor(idx, off);
        if (v2 > v || (v2 == v && i2 < idx)) { v = v2; idx = i2; }
    }
    if (lane == 0) { wv[wave] = v; widx[wave] = idx; }
    __syncthreads();

    if (h == 0) {
        float bv = wv[0];
        int bi = widx[0];
#pragma unroll
        for (int k = 1; k < 8; ++k) {
            if (wv[k] > bv || (wv[k] == bv && widx[k] < bi)) { bv = wv[k]; bi = widx[k]; }
        }
        s_max = bv;
        s_maxidx = bi;
    }
    __syncthreads();

    // softmax weights + weighted loss
    float wgt = __expf(0.5f * (s - s_max));
    float wl = wgt * l;
#pragma unroll
    for (int off = 32; off; off >>= 1) {
        wgt += __shfl_xor(wgt, off);
        wl += __shfl_xor(wl, off);
    }
    if (lane == 0) { sw[wave] = wgt; swl[wave] = wl; }
    __syncthreads();

    if (h == 0) {
        float tw = 0.f, twl = 0.f;
#pragma unroll
        for (int k = 0; k < 8; ++k) { tw += sw[k]; twl += swl[k]; }
        const int mi = s_maxidx;
        out[b] = twl / tw;                                   // exp_loss
        out[B + b] = loss[b * H + mi];                       // top_loss
        out[2 * B + b * 3 + 0] = normals[(b * H + mi) * 3 + 0];
        out[2 * B + b * 3 + 1] = normals[(b * H + mi) * 3 + 1];
        out[2 * B + b * 3 + 2] = normals[(b * H + mi) * 3 + 2];
    }
}

// ---------------------------------------------------------------------------
extern "C" void kernel_launch(void* const* d_in, const int* in_sizes, int n_in,
                              void* d_out, int out_size, void* d_ws, size_t ws_size,
                              hipStream_t stream) {
    const float* pts       = (const float*)d_in[0];  // (B,3,N)
    const float* target    = (const float*)d_in[1];  // (B,3)
    const float* pt_weight = (const float*)d_in[2];  // (B,N)
    const int*   sel_idx   = (const int*)d_in[3];    // (B,H,3)

    float* out = (float*)d_out;
    // layout: exp_loss[B] | top_loss[B] | pred[B*3] | gpts[B*G*3]
    float* out_gpts = out + B + B + 3 * B;  // offset 320

    float* ws      = (float*)d_ws;
    float* score   = ws;                  // B*H
    float* loss    = ws + B * H;          // B*H
    float* normals = ws + 2 * B * H;      // B*H*3

    topk_gather_kernel<<<B * TKB, 256, 0, stream>>>(pts, pt_weight, out_gpts);
    plane_score_kernel<<<B * (H / HB), 256, 0, stream>>>(pts, target, sel_idx,
                                                         out_gpts, score, loss, normals);
    finalize_kernel<<<B, H, 0, stream>>>(score, loss, normals, out);
}